// Round 13
// baseline (114.372 us; speedup 1.0000x reference)
//
#include <hip/hip_runtime.h>
#include <math.h>

#define N_PTS   10000
#define CIN     64
#define COUT    32
#define KCAP    32
#define RADIUSF 0.07f
#define NCELLS  27
#define QB      8      // queries per block (8 waves; wave w owns query w; MFMA rows 0-7)
#define MAXC    48     // per-query in-radius cap (Poisson(14.4): P(>48) ~ 1e-12)
#define GRES    14     // hash grid resolution; 1/14 = 0.0714 > R = 0.07
#define GCELLS  (GRES * GRES * GRES)   // 2744
#define CPAD    72     // sAb bf16 row stride: 144 B -> b128-aligned
#define NSCAT   40     // scatter blocks in k2
#define WT_ELEMS (NCELLS * COUT * CIN) // 55296

typedef __attribute__((ext_vector_type(8))) short         bf16x8_t;
typedef __attribute__((ext_vector_type(4))) float         f32x4_t;

__device__ __forceinline__ void cell_coords(float x, float y, float z,
                                            int& cx, int& cy, int& cz) {
    cx = (int)(x * (float)GRES); if (cx > GRES - 1) cx = GRES - 1; if (cx < 0) cx = 0;
    cy = (int)(y * (float)GRES); if (cy > GRES - 1) cy = GRES - 1; if (cy < 0) cy = 0;
    cz = (int)(z * (float)GRES); if (cz > GRES - 1) cz = GRES - 1; if (cz < 0) cz = 0;
}

// fp32 -> bf16 round-to-nearest-even, raw bits (finite inputs)
__device__ __forceinline__ unsigned int f2bf_u(float x) {
    unsigned int u = __float_as_uint(x);
    return (u + 0x7FFFu + ((u >> 16) & 1u)) >> 16;
}

// ---- build k1 (28 blocks x 1024): block 0 = LDS histogram + shfl scan ->
// ---- offsets/cursor; blocks 1..27 = W[cell] f32->bf16 transpose (independent).
__global__ __launch_bounds__(1024) void k1_hist_scan_wt(
    const float* __restrict__ pts,
    const float* __restrict__ W,
    int* __restrict__ offsets,    // GCELLS+1
    int* __restrict__ cursor,     // GCELLS
    unsigned short* __restrict__ Wt)
{
    const int t = threadIdx.x;
    const int b = blockIdx.x;

    if (b >= 1) {   // W transpose for cell b-1
        __shared__ float tile[CIN * 33];
        const int cell = b - 1;
        for (int idx = t; idx < CIN * COUT; idx += 1024) {
            int f = idx >> 5, o = idx & 31;
            tile[f * 33 + o] = W[cell * (CIN * COUT) + idx];    // coalesced read
        }
        __syncthreads();
        for (int idx = t; idx < CIN * COUT; idx += 1024) {
            int o = idx >> 6, f = idx & 63;
            Wt[cell * (CIN * COUT) + idx] = (unsigned short)f2bf_u(tile[f * 33 + o]);
        }
        return;
    }

    __shared__ int s_hist[GCELLS];
    __shared__ int s_wsum[16];
    const int lane = t & 63;
    const int wv   = t >> 6;

    for (int i = t; i < GCELLS; i += 1024) s_hist[i] = 0;
    __syncthreads();
    for (int i = t; i < N_PTS; i += 1024) {
        int cx, cy, cz;
        cell_coords(pts[3 * i], pts[3 * i + 1], pts[3 * i + 2], cx, cy, cz);
        atomicAdd(&s_hist[(cx * GRES + cy) * GRES + cz], 1);
    }
    __syncthreads();

    const int c0 = t * 3;
    int v0 = (c0 + 0 < GCELLS) ? s_hist[c0 + 0] : 0;
    int v1 = (c0 + 1 < GCELLS) ? s_hist[c0 + 1] : 0;
    int v2 = (c0 + 2 < GCELLS) ? s_hist[c0 + 2] : 0;
    const int local = v0 + v1 + v2;
    int inc = local;
    #pragma unroll
    for (int d = 1; d < 64; d <<= 1) {
        int up = __shfl_up(inc, d);
        if (lane >= d) inc += up;
    }
    if (lane == 63) s_wsum[wv] = inc;
    __syncthreads();
    if (t == 0) {
        int run = 0;
        #pragma unroll
        for (int i = 0; i < 16; ++i) { int tmp = s_wsum[i]; s_wsum[i] = run; run += tmp; }
    }
    __syncthreads();
    int base = s_wsum[wv] + (inc - local);
    if (c0 + 0 < GCELLS) { offsets[c0 + 0] = base; cursor[c0 + 0] = base; base += v0; }
    if (c0 + 1 < GCELLS) { offsets[c0 + 1] = base; cursor[c0 + 1] = base; base += v1; }
    if (c0 + 2 < GCELLS) { offsets[c0 + 2] = base; cursor[c0 + 2] = base; base += v2; }
    if (t == 0) offsets[GCELLS] = N_PTS;
}

// ---- build k2 (40 blocks x 256): scatter indices + cell-sorted point copies ----
__global__ __launch_bounds__(256) void k2_scatter(
    const float* __restrict__ pts,
    int*   __restrict__ cursor,
    int*   __restrict__ sorted,
    float* __restrict__ pts_s)
{
    const int b = blockIdx.x;
    const int t = threadIdx.x;
    const int per = N_PTS / NSCAT;    // 250
    const int lo = b * per;
    const int hi = lo + per;
    for (int i = lo + t; i < hi; i += 256) {
        float x = pts[3 * i + 0], y = pts[3 * i + 1], z = pts[3 * i + 2];
        int cx, cy, cz;
        cell_coords(x, y, z, cx, cy, cz);
        int cell = (cx * GRES + cy) * GRES + cz;
        int pos = atomicAdd(&cursor[cell], 1);
        sorted[pos] = i;
        pts_s[3 * pos + 0] = x;   // bitwise copies -> d2 stays byte-identical
        pts_s[3 * pos + 1] = y;
        pts_s[3 * pos + 2] = z;
    }
}

// ---- main fused kernel: 8 queries/block, ~37.6 KB LDS -> 4 blocks/CU ----
__global__ __launch_bounds__(512) void cconv_grid_mfma_kernel(
    const float* __restrict__ feats,
    const unsigned short* __restrict__ Wt,   // [27][32][64] bf16
    const float* __restrict__ bias,
    const int*   __restrict__ offsets,
    const int*   __restrict__ sorted,
    const float* __restrict__ pts_s,
    float* __restrict__ out)
{
    const int tid  = threadIdx.x;
    const int lane = tid & 63;
    const int wave = tid >> 6;

    __shared__ __align__(16) unsigned short sAb[QB][NCELLS + 1][CPAD];  // 32256 B
    __shared__ __align__(16) float s_scratch[QB * 4 * MAXC];            // 6144 B: pool; later sC[8][32]
    __shared__ int   s_cnt[QB];
    __shared__ int   s_qi[QB];
    __shared__ int   s_nn[QB];

    float (*s_pool)[4][MAXC] = (float (*)[4][MAXC])s_scratch;

    // per-wave overlays in the (dead until phase-2b store) sAb region: 4032 B/wave
    char*  wbase = (char*)&sAb[wave][0][0];
    float* w9w   = (float*)wbase;               // [32][12] floats = 1536 B
    int*   s_idxw = (int*)(wbase + 1536);       // 48 ints
    int*   s_orgw = (int*)(wbase + 1728);       // 48 ints
    int*   s_selw = (int*)(wbase + 1920);       // 32 ints (ends at 2048 <= 4032)

    if (lane == 0) s_cnt[wave] = 0;

    const int q_flat = blockIdx.x * QB + wave;
    const int qi = sorted[q_flat];
    const float qx = pts_s[3 * q_flat + 0];   // == points[qi], bitwise
    const float qy = pts_s[3 * q_flat + 1];
    const float qz = pts_s[3 * q_flat + 2];
    const float sqn = qx * qx + qy * qy + qz * qz;
    const float r2 = RADIUSF * RADIUSF;

    int cx, cy, cz;
    cell_coords(qx, qy, qz, cx, cy, cz);

    // ---- Phase 1: flattened candidate scan; adj[]-select (2 inst/segment) ----
    int zlo = cz - 1; if (zlo < 0) zlo = 0;
    int zhi = cz + 1; if (zhi > GRES - 1) zhi = GRES - 1;
    int adj[9], cum[10];
    cum[0] = 0;
    #pragma unroll
    for (int dxi = 0; dxi < 3; ++dxi) {
        #pragma unroll
        for (int dyi = 0; dyi < 3; ++dyi) {
            const int ii = dxi * 3 + dyi;
            int cxx = cx + dxi - 1, cyy = cy + dyi - 1;
            bool ok = (cxx >= 0) && (cxx <= GRES - 1) && (cyy >= 0) && (cyy <= GRES - 1);
            int row = ((ok ? cxx : 0) * GRES + (ok ? cyy : 0)) * GRES;
            int s = offsets[row + zlo];
            int e = offsets[row + zhi + 1];
            int len = ok ? (e - s) : 0;
            adj[ii] = s - cum[ii];
            cum[ii + 1] = cum[ii] + len;
        }
    }
    const int T = cum[9];

    for (int t = lane; t < T; t += 64) {
        int a = adj[0];
        #pragma unroll
        for (int ii = 1; ii < 9; ++ii) a = (t >= cum[ii]) ? adj[ii] : a;
        const int gidx = a + t;
        float x = pts_s[3 * gidx + 0];
        float y = pts_s[3 * gidx + 1];
        float z = pts_s[3 * gidx + 2];
        float sqj = x * x + y * y + z * z;
        float dot = qx * x + qy * y + qz * z;
        float d2 = (sqn + sqj) - 2.0f * dot;   // byte-identical to ref form
        if (d2 <= r2) {
            int pos = atomicAdd(&s_cnt[wave], 1);
            if (pos < MAXC) {
                s_pool[wave][0][pos] = d2;
                s_pool[wave][1][pos] = x;
                s_pool[wave][2][pos] = y;
                s_pool[wave][3][pos] = z;
                s_idxw[pos] = gidx;
            }
        }
    }

    int M = s_cnt[wave]; if (M > MAXC) M = MAXC;
    const int cnt = (M > KCAP) ? KCAP : M;
    const bool over = (M > KCAP);

    if (lane < M) s_orgw[lane] = sorted[s_idxw[lane]];   // batch resolve

    if (over) {   // exact top-32; tie-break matches lax.top_k (d2, then original index)
        if (lane < M) {
            float dc = s_pool[wave][0][lane];
            int   ic = s_orgw[lane];
            int rank = 0;
            for (int m = 0; m < M; ++m) {
                float dm = s_pool[wave][0][m];
                int   im = s_orgw[m];
                rank += (dm < dc || (dm == dc && im < ic)) ? 1 : 0;
            }
            if (rank < KCAP) s_selw[rank] = lane;   // store SLOT
        }
    }
    if (lane == 0) { s_qi[wave] = qi; s_nn[wave] = cnt; }

    // ---- Phase 2a: per-neighbor trilinear weights computed ONCE, in parallel ----
    if (lane < cnt) {
        int slot = over ? s_selw[lane] : lane;
        float x = s_pool[wave][1][slot];
        float y = s_pool[wave][2][slot];
        float z = s_pool[wave][3][slot];
        int   j = s_orgw[slot];
        float rx = (x - qx) / RADIUSF;
        float ry = (y - qy) / RADIUSF;
        float rz = (z - qz) / RADIUSF;
        float l2 = sqrtf(rx * rx + ry * ry + rz * rz);
        float ax = fabsf(rx), ay = fabsf(ry), az = fabsf(rz);
        float linf = fmaxf(fmaxf(ax, ay), az);
        float s = (linf > 0.0f) ? (l2 / fmaxf(linf, 1e-12f)) : 0.0f;
        float tx = rx * s, ty = ry * s, tz = rz * s;
        float cxf = (tx + 1.0f) * 0.5f * 2.0f;
        float cyf = (ty + 1.0f) * 0.5f * 2.0f;
        float czf = (tz + 1.0f) * 0.5f * 2.0f;
        float c0x = fminf(fmaxf(floorf(cxf), 0.0f), 1.0f);
        float c0y = fminf(fmaxf(floorf(cyf), 0.0f), 1.0f);
        float c0z = fminf(fmaxf(floorf(czf), 0.0f), 1.0f);
        float fx = cxf - c0x;
        float fy = cyf - c0y;
        float fz = czf - c0z;
        int i0 = (int)c0x, i1 = (int)c0y, i2 = (int)c0z;
        float gx0 = 1.0f - fx, gx1 = fx;
        float gy0 = 1.0f - fy, gy1 = fy;
        float gz0 = 1.0f - fz, gz1 = fz;
        float* wp = w9w + lane * 12;
        wp[0] = i0 ? 0.0f : gx0;  wp[1] = i0 ? gx0 : gx1;  wp[2]  = i0 ? gx1 : 0.0f;
        wp[3] = i1 ? 0.0f : gy0;  wp[4] = i1 ? gy0 : gy1;  wp[5]  = i1 ? gy1 : 0.0f;
        wp[6] = i2 ? 0.0f : gz0;  wp[7] = i2 ? gz0 : gz1;  wp[8]  = i2 ? gz1 : 0.0f;
        wp[9] = __int_as_float(j * CIN);
        wp[10] = 0.0f; wp[11] = 0.0f;
    }

    // ---- Phase 2b: register-accumulated scatter (lane = feature), depth-2 prefetch ----
    float a[NCELLS];
    #pragma unroll
    for (int c = 0; c < NCELLS; ++c) a[c] = 0.0f;

    if (cnt > 0) {
        float fvA = feats[__float_as_int(w9w[9]) + lane];
        float fvB = 0.0f;
        if (cnt > 1) fvB = feats[__float_as_int(w9w[12 + 9]) + lane];
        for (int k = 0; k < cnt; ++k) {
            const float* wp = w9w + k * 12;
            f32x4_t wv0 = *(const f32x4_t*)(wp);       // wx0 wx1 wx2 wy0
            f32x4_t wv1 = *(const f32x4_t*)(wp + 4);   // wy1 wy2 wz0 wz1
            float   wz2 = wp[8];
            float wxv[3] = {wv0[0], wv0[1], wv0[2]};
            float wyv[3] = {wv0[3], wv1[0], wv1[1]};
            float fv_cur = fvA;
            fvA = fvB;
            if (k + 2 < cnt) fvB = feats[__float_as_int(w9w[(k + 2) * 12 + 9]) + lane];
            float pzv[3] = {wv1[2] * fv_cur, wv1[3] * fv_cur, wz2 * fv_cur};
            #pragma unroll
            for (int ci = 0; ci < 3; ++ci) {
                #pragma unroll
                for (int cj = 0; cj < 3; ++cj) {
                    float wxy = wxv[ci] * wyv[cj];
                    #pragma unroll
                    for (int ck = 0; ck < 3; ++ck) {
                        a[ci * 9 + cj * 3 + ck] = fmaf(wxy, pzv[ck], a[ci * 9 + cj * 3 + ck]);
                    }
                }
            }
        }
    }
    #pragma unroll
    for (int c = 0; c < NCELLS; ++c) sAb[wave][c][lane] = (unsigned short)f2bf_u(a[c]);
    sAb[wave][NCELLS][lane] = 0;     // zero pad row
    __syncthreads();                 // all pools/overlays dead; sAb complete

    // zero sC[8][32] overlay, then reduce via LDS atomics
    if (tid < 256) s_scratch[tid] = 0.0f;
    __syncthreads();

    // ---- Phase 3: MFMA contraction, 56 padded K-steps, 7/wave, depth-2 SW pipeline ----
    f32x4_t acc0 = {0.f, 0.f, 0.f, 0.f};
    f32x4_t acc1 = {0.f, 0.f, 0.f, 0.f};
    const int r  = lane & 15;
    const int kg = lane >> 4;

    const int s5_0 = wave;
    const int c_0  = s5_0 >> 1;
    const int f_0  = (s5_0 & 1) << 5;
    bf16x8_t aCur = {}, bCur0, bCur1;
    if (r < QB) aCur = *(const bf16x8_t*)&sAb[r][c_0][f_0 + kg * 8];
    bCur0 = *(const bf16x8_t*)(Wt + ((c_0 * COUT + r     ) * CIN + f_0 + kg * 8));
    bCur1 = *(const bf16x8_t*)(Wt + ((c_0 * COUT + 16 + r) * CIN + f_0 + kg * 8));

    #pragma unroll
    for (int it = 0; it < 7; ++it) {
        bf16x8_t aNxt = {}, bNxt0 = {}, bNxt1 = {};
        if (it + 1 < 7) {
            const int s5n = wave + (it + 1) * 8;
            const int cn  = s5n >> 1;
            const int fn  = (s5n & 1) << 5;
            const int cwn = (cn < NCELLS) ? cn : 0;
            if (r < QB) aNxt = *(const bf16x8_t*)&sAb[r][cn][fn + kg * 8];
            bNxt0 = *(const bf16x8_t*)(Wt + ((cwn * COUT + r     ) * CIN + fn + kg * 8));
            bNxt1 = *(const bf16x8_t*)(Wt + ((cwn * COUT + 16 + r) * CIN + fn + kg * 8));
        }
        acc0 = __builtin_amdgcn_mfma_f32_16x16x32_bf16(aCur, bCur0, acc0, 0, 0, 0);
        acc1 = __builtin_amdgcn_mfma_f32_16x16x32_bf16(aCur, bCur1, acc1, 0, 0, 0);
        aCur = aNxt; bCur0 = bNxt0; bCur1 = bNxt1;
    }

    // cross-wave reduce: lanes 0-31 hold rows 0-7 (row = 4*kg + reg)
    float (*sC)[COUT] = (float (*)[COUT])s_scratch;
    if (lane < 32) {
        int qrow = (lane >> 4) * 4;
        int o = lane & 15;
        #pragma unroll
        for (int j = 0; j < 4; ++j) {
            atomicAdd(&sC[qrow + j][o],      acc0[j]);
            atomicAdd(&sC[qrow + j][16 + o], acc1[j]);
        }
    }
    __syncthreads();

    if (tid < QB * COUT) {
        int q = tid >> 5, o = tid & 31;
        float nn = (float)s_nn[q];
        out[s_qi[q] * COUT + o] = sC[q][o] / fmaxf(nn, 1.0f) + bias[o];
    }
}

// ---- fallback (validated Round-3 kernel) if workspace is too small ----
__global__ __launch_bounds__(64) void cconv_fused_kernel(
    const float* __restrict__ feats,
    const float* __restrict__ points,
    const float* __restrict__ W,
    const float* __restrict__ bias,
    float* __restrict__ out)
{
    const int n    = blockIdx.x;
    const int lane = threadIdx.x;

    __shared__ float sA[NCELLS][CIN];
    __shared__ float s_d2[128];
    __shared__ int   s_idx[128];
    __shared__ int   s_rank[128];
    __shared__ int   s_sel[KCAP];
    __shared__ int   s_cnt;

    if (lane == 0) s_cnt = 0;
    for (int c = lane; c < NCELLS * CIN; c += 64) ((float*)sA)[c] = 0.0f;
    __syncthreads();

    const float qx = points[3 * n + 0];
    const float qy = points[3 * n + 1];
    const float qz = points[3 * n + 2];
    const float sqn = qx * qx + qy * qy + qz * qz;
    const float r2 = RADIUSF * RADIUSF;

    for (int j = lane; j < N_PTS; j += 64) {
        float x = points[3 * j + 0];
        float y = points[3 * j + 1];
        float z = points[3 * j + 2];
        float sqj = x * x + y * y + z * z;
        float dot = qx * x + qy * y + qz * z;
        float d2 = (sqn + sqj) - 2.0f * dot;
        if (d2 <= r2) {
            int pos = atomicAdd(&s_cnt, 1);
            if (pos < 128) { s_d2[pos] = d2; s_idx[pos] = j; }
        }
    }
    __syncthreads();

    int M = s_cnt; if (M > 128) M = 128;
    int cnt;
    if (M > KCAP) {
        for (int c = lane; c < M; c += 64) {
            float dc = s_d2[c]; int ic = s_idx[c]; int rank = 0;
            for (int m = 0; m < M; ++m) {
                float dm = s_d2[m]; int im = s_idx[m];
                rank += (dm < dc || (dm == dc && im < ic)) ? 1 : 0;
            }
            s_rank[c] = rank;
        }
        __syncthreads();
        for (int c = lane; c < M; c += 64) {
            int r = s_rank[c];
            if (r < KCAP) s_sel[r] = s_idx[c];
        }
        __syncthreads();
        cnt = KCAP;
    } else cnt = M;
    const int* nbr = (M > KCAP) ? s_sel : s_idx;

    for (int k = 0; k < cnt; ++k) {
        int j = nbr[k];
        float x = points[3 * j + 0];
        float y = points[3 * j + 1];
        float z = points[3 * j + 2];
        float rx = (x - qx) / RADIUSF;
        float ry = (y - qy) / RADIUSF;
        float rz = (z - qz) / RADIUSF;
        float l2 = sqrtf(rx * rx + ry * ry + rz * rz);
        float ax = fabsf(rx), ay = fabsf(ry), az = fabsf(rz);
        float linf = fmaxf(fmaxf(ax, ay), az);
        float s = (linf > 0.0f) ? (l2 / fmaxf(linf, 1e-12f)) : 0.0f;
        float tx = rx * s, ty = ry * s, tz = rz * s;
        float cxf = (tx + 1.0f) * 0.5f * 2.0f;
        float cyf = (ty + 1.0f) * 0.5f * 2.0f;
        float czf = (tz + 1.0f) * 0.5f * 2.0f;
        float c0x = fminf(fmaxf(floorf(cxf), 0.0f), 1.0f);
        float c0y = fminf(fmaxf(floorf(cyf), 0.0f), 1.0f);
        float c0z = fminf(fmaxf(floorf(czf), 0.0f), 1.0f);
        float fx = cxf - c0x, fy = cyf - c0y, fz = czf - c0z;
        int i0 = (int)c0x, i1 = (int)c0y, i2 = (int)c0z;
        int base = i0 * 9 + i1 * 3 + i2;
        float gx0 = 1.0f - fx, gx1 = fx;
        float gy0 = 1.0f - fy, gy1 = fy;
        float gz0 = 1.0f - fz, gz1 = fz;
        float featv = feats[j * CIN + lane];
        sA[base + 0 ][lane] += (gx0 * gy0) * gz0 * featv;
        sA[base + 1 ][lane] += (gx0 * gy0) * gz1 * featv;
        sA[base + 3 ][lane] += (gx0 * gy1) * gz0 * featv;
        sA[base + 4 ][lane] += (gx0 * gy1) * gz1 * featv;
        sA[base + 9 ][lane] += (gx1 * gy0) * gz0 * featv;
        sA[base + 10][lane] += (gx1 * gy0) * gz1 * featv;
        sA[base + 12][lane] += (gx1 * gy1) * gz0 * featv;
        sA[base + 13][lane] += (gx1 * gy1) * gz1 * featv;
    }
    __syncthreads();

    const int o    = lane & 31;
    const int half = lane >> 5;
    const int c_begin = half ? 14 : 0;
    const int c_end   = half ? 27 : 14;
    float acc = 0.0f;
    for (int cell = c_begin; cell < c_end; ++cell) {
        const float* __restrict__ Wrow = W + (cell * CIN) * COUT + o;
        #pragma unroll 8
        for (int f = 0; f < CIN; ++f) acc += sA[cell][f] * Wrow[f * COUT];
    }
    acc += __shfl_xor(acc, 32);
    if (lane < COUT) {
        float nn = (float)cnt;
        out[n * COUT + lane] = acc / fmaxf(nn, 1.0f) + bias[lane];
    }
}

extern "C" void kernel_launch(void* const* d_in, const int* in_sizes, int n_in,
                              void* d_out, int out_size, void* d_ws, size_t ws_size,
                              hipStream_t stream) {
    const float* feats  = (const float*)d_in[0];
    const float* points = (const float*)d_in[1];
    const float* W      = (const float*)d_in[2];
    const float* bias   = (const float*)d_in[3];
    float* out = (float*)d_out;

    // ws layout: Wt bf16 | offsets | cursor | sorted | pts_s
    const size_t wt_bytes = (size_t)WT_ELEMS * sizeof(unsigned short);   // 110592
    const size_t need     = wt_bytes
                          + (size_t)(GCELLS + 1 + GCELLS + N_PTS) * sizeof(int)
                          + (size_t)3 * N_PTS * sizeof(float);

    if (ws_size >= need) {
        unsigned short* Wt = (unsigned short*)d_ws;
        int* offsets = (int*)((char*)d_ws + wt_bytes);   // GCELLS+1
        int* cursor  = offsets + GCELLS + 1;             // GCELLS
        int* sorted  = cursor + GCELLS;                  // N_PTS
        float* pts_s = (float*)(sorted + N_PTS);         // 3*N_PTS

        k1_hist_scan_wt<<<1 + NCELLS, 1024, 0, stream>>>(points, W, offsets, cursor, Wt);
        k2_scatter<<<NSCAT, 256, 0, stream>>>(points, cursor, sorted, pts_s);
        cconv_grid_mfma_kernel<<<N_PTS / QB, QB * 64, 0, stream>>>(
            feats, Wt, bias, offsets, sorted, pts_s, out);
    } else {
        cconv_fused_kernel<<<N_PTS, 64, 0, stream>>>(feats, points, W, bias, out);
    }
}